// Round 3
// baseline (5078.184 us; speedup 1.0000x reference)
//
#include <hip/hip_runtime.h>
#include <hip/hip_bf16.h>
#include <math.h>

// MoEGate: scores = sigmoid(x @ W^T); group top-2-sum -> top-4 groups -> top-8
// experts -> normalized weights * 2.5.
// Phase 1: fp32 vector GEMM (no fp32 MFMA on CDNA4), K-split=7 for occupancy,
//          partials in ws. 8x8/lane micro-tile: 0.25 LDS floats/FMA = LDS BW
//          break-even (128 B/clk/CU). BK=16 -> 10 KB LDS -> not LDS-capped.
// Phase 2: one WAVE per token, register-resident scores, shuffle reductions.

constexpr int T_TOK = 8192;
constexpr int HID   = 7168;
constexpr int NEXP  = 256;

constexpr int BM = 64, BN = 64, BK = 16;
constexpr int KSPLIT = 7;
constexpr int KHALF  = HID / KSPLIT;   // 1024 -> 64 K-tiles of 16
constexpr int LDS4   = 5;              // float4 stride per row (4 data + 1 pad)

__global__ __launch_bounds__(64, 3)
void gemm_partial(const float* __restrict__ x, const float* __restrict__ w,
                  float* __restrict__ part) {
  __shared__ float4 As4[BM * LDS4];
  __shared__ float4 Bs4[BN * LDS4];
  const int lane = threadIdx.x;
  const int e0 = blockIdx.x * BN;     // expert tile (fastest -> x reuse in L2)
  const int t0 = blockIdx.y * BM;     // token tile
  const int kp = blockIdx.z;          // k-split slice
  const size_t kbase = (size_t)kp * KHALF;

  // compute mapping: 8x8 micro-tile
  const int tx = lane & 7;            // expert sub
  const int ty = lane >> 3;           // token sub
  // staging mapping: 16 rows x 4 float4-cols per pass, 4 passes
  const int sc = lane & 3;
  const int sr = lane >> 2;

  float acc[8][8];
#pragma unroll
  for (int i = 0; i < 8; ++i)
#pragma unroll
    for (int j = 0; j < 8; ++j) acc[i][j] = 0.f;

  const float* xs = x + (size_t)(t0 + sr) * HID + kbase + 4 * sc;
  const float* wsrc = w + (size_t)(e0 + sr) * HID + kbase + 4 * sc;

  float4 pa[4], pb[4];
#pragma unroll
  for (int p = 0; p < 4; ++p) {
    pa[p] = *(const float4*)(xs + (size_t)(16 * p) * HID);
    pb[p] = *(const float4*)(wsrc + (size_t)(16 * p) * HID);
  }

  for (int k0 = 0; k0 < KHALF; k0 += BK) {
    __syncthreads();
#pragma unroll
    for (int p = 0; p < 4; ++p) {
      As4[(sr + 16 * p) * LDS4 + sc] = pa[p];
      Bs4[(sr + 16 * p) * LDS4 + sc] = pb[p];
    }
    __syncthreads();
    if (k0 + BK < KHALF) {
#pragma unroll
      for (int p = 0; p < 4; ++p) {
        pa[p] = *(const float4*)(xs + (size_t)(16 * p) * HID + (k0 + BK));
        pb[p] = *(const float4*)(wsrc + (size_t)(16 * p) * HID + (k0 + BK));
      }
    }
#pragma unroll
    for (int q = 0; q < 4; ++q) {     // 4 k's per step
      float4 av[8], bv[8];
#pragma unroll
      for (int i = 0; i < 8; ++i) av[i] = As4[(ty + 8 * i) * LDS4 + q];
#pragma unroll
      for (int j = 0; j < 8; ++j) bv[j] = Bs4[(tx + 8 * j) * LDS4 + q];
#pragma unroll
      for (int i = 0; i < 8; ++i)
#pragma unroll
        for (int j = 0; j < 8; ++j) {
          acc[i][j] += av[i].x * bv[j].x;
          acc[i][j] += av[i].y * bv[j].y;
          acc[i][j] += av[i].z * bv[j].z;
          acc[i][j] += av[i].w * bv[j].w;
        }
    }
  }

  float* pout = part + (size_t)kp * T_TOK * NEXP;
#pragma unroll
  for (int i = 0; i < 8; ++i) {
    const size_t t = t0 + ty + 8 * i;
#pragma unroll
    for (int j = 0; j < 8; ++j)
      pout[t * NEXP + (e0 + tx + 8 * j)] = acc[i][j];
  }
}

// one wave per token; lane l owns experts 4l..4l+3 entirely in registers
__global__ __launch_bounds__(256)
void routing_kernel(const float* __restrict__ part,
                    const float* __restrict__ bias,
                    float* __restrict__ out) {
  const int lane = threadIdx.x & 63;
  const int t = blockIdx.x * 4 + (threadIdx.x >> 6);
  const int e_base = 4 * lane;

  // reduce K-split partials, sigmoid, add bias
  float4 z = make_float4(0.f, 0.f, 0.f, 0.f);
#pragma unroll
  for (int kp = 0; kp < KSPLIT; ++kp) {
    float4 v = *(const float4*)(part + (size_t)kp * T_TOK * NEXP +
                                (size_t)t * NEXP + e_base);
    z.x += v.x; z.y += v.y; z.z += v.z; z.w += v.w;
  }
  float s[4], sb[4];
  const float4 b4 = *(const float4*)(bias + e_base);
  s[0] = 1.f / (1.f + expf(-z.x)); sb[0] = s[0] + b4.x;
  s[1] = 1.f / (1.f + expf(-z.y)); sb[1] = s[1] + b4.y;
  s[2] = 1.f / (1.f + expf(-z.z)); sb[2] = s[2] + b4.z;
  s[3] = 1.f / (1.f + expf(-z.w)); sb[3] = s[3] + b4.w;

  // lane-local top-2 of 4 (pairwise tournament):
  //   second-max = max( min(Ma,Mb), max(ma,mb) )  [m_loser <= min(Ma,Mb)]
  const float Ma = fmaxf(sb[0], sb[1]), ma = fminf(sb[0], sb[1]);
  const float Mb = fmaxf(sb[2], sb[3]), mb = fminf(sb[2], sb[3]);
  float m1 = fmaxf(Ma, Mb);
  float m2 = fmaxf(fminf(Ma, Mb), fmaxf(ma, mb));
  // merge (m1,m2) pairs across the 8 lanes of the group via shfl_xor 1,2,4
#pragma unroll
  for (int off = 1; off < 8; off <<= 1) {
    const float o1 = __shfl_xor(m1, off);
    const float o2 = __shfl_xor(m2, off);
    const float n1 = fmaxf(m1, o1);
    m2 = fmaxf(fminf(m1, o1), fmaxf(m2, o2));
    m1 = n1;
  }
  const float gsum = m1 + m2;   // identical across the 8 lanes of each group

  // all 8 group sums to every lane
  float gs[8];
#pragma unroll
  for (int g = 0; g < 8; ++g) gs[g] = __shfl(gsum, g * 8);

  // stable top-4 groups (strict >, ascending scan -> lowest index on ties)
  unsigned gmask = 0;
#pragma unroll
  for (int r = 0; r < 4; ++r) {
    int best = 0; float bv = -3.4e38f;
#pragma unroll
    for (int g = 0; g < 8; ++g) {
      const bool ok = (((gmask >> g) & 1u) == 0) && (gs[g] > bv);
      bv = ok ? gs[g] : bv;
      best = ok ? g : best;
    }
    gmask |= 1u << best;
  }

  // mask out unselected groups
  const bool sel = (gmask >> (lane >> 3)) & 1u;
#pragma unroll
  for (int j = 0; j < 4; ++j) sb[j] = sel ? sb[j] : -3.4e38f;

  // top-8 experts: 8 rounds of wave-argmax (ties -> lowest expert index)
  float wq[8]; float iq[8];
#pragma unroll
  for (int r = 0; r < 8; ++r) {
    float bv = sb[0]; int bi = e_base; float bs = s[0];
#pragma unroll
    for (int j = 1; j < 4; ++j) {
      const bool c = sb[j] > bv;
      bv = c ? sb[j] : bv; bi = c ? e_base + j : bi; bs = c ? s[j] : bs;
    }
#pragma unroll
    for (int off = 1; off < 64; off <<= 1) {
      const float ov = __shfl_xor(bv, off);
      const int   oi = __shfl_xor(bi, off);
      const float os = __shfl_xor(bs, off);
      const bool take = (ov > bv) || (ov == bv && oi < bi);
      bv = take ? ov : bv; bi = take ? oi : bi; bs = take ? os : bs;
    }
    wq[r] = bs; iq[r] = (float)bi;
#pragma unroll
    for (int j = 0; j < 4; ++j)
      if (e_base + j == bi) sb[j] = -3.4e38f;
  }

  float wsum = 1e-20f;
#pragma unroll
  for (int r = 0; r < 8; ++r) wsum += wq[r];
  const float scale = 2.5f / wsum;

  if (lane == 0) {
    float4* ow = (float4*)(out + (size_t)t * 8);
    ow[0] = make_float4(wq[0] * scale, wq[1] * scale, wq[2] * scale, wq[3] * scale);
    ow[1] = make_float4(wq[4] * scale, wq[5] * scale, wq[6] * scale, wq[7] * scale);
    float4* oi = (float4*)(out + (size_t)T_TOK * 8 + (size_t)t * 8);
    oi[0] = make_float4(iq[0], iq[1], iq[2], iq[3]);
    oi[1] = make_float4(iq[4], iq[5], iq[6], iq[7]);
  }
}

extern "C" void kernel_launch(void* const* d_in, const int* in_sizes, int n_in,
                              void* d_out, int out_size, void* d_ws, size_t ws_size,
                              hipStream_t stream) {
  const float* x    = (const float*)d_in[0];
  const float* w    = (const float*)d_in[1];
  const float* bias = (const float*)d_in[2];
  float* out  = (float*)d_out;
  float* part = (float*)d_ws;   // [KSPLIT][T_TOK][NEXP] fp32 = 57.3 MB

  dim3 ggrid(NEXP / BN, T_TOK / BM, KSPLIT);   // (4, 128, 7) = 3584 blocks
  hipLaunchKernelGGL(gemm_partial, ggrid, dim3(64), 0, stream, x, w, part);
  hipLaunchKernelGGL(routing_kernel, dim3(T_TOK / 4), dim3(256), 0, stream,
                     part, bias, out);
}

// Round 4
// 1097.586 us; speedup vs baseline: 4.6267x; 4.6267x over previous
//
#include <hip/hip_runtime.h>
#include <hip/hip_bf16.h>
#include <math.h>

// MoEGate: scores = sigmoid(x @ W^T); group top-2-sum -> top-4 groups -> top-8
// experts -> normalized weights * 2.5.
// Phase 1: fp32 vector GEMM (no fp32 MFMA on CDNA4), K-split=7, partials in ws.
//   Register discipline: NO persistent prefetch regs, q-loop not unrolled,
//   one bv live at a time -> peak live ~105 VGPR, no spills (R3 post-mortem:
//   __launch_bounds__(64,3) forced 84 VGPR -> acc spilled -> 19.6 GB HBM).
//   1-wave blocks: __syncthreads is wave-private; TLP across blocks hides
//   global latency, so prefetch is unnecessary.
// Phase 2: one WAVE per token, register-resident scores, shuffle reductions.

constexpr int T_TOK = 8192;
constexpr int HID   = 7168;
constexpr int NEXP  = 256;

constexpr int BM = 64, BN = 64, BK = 16;
constexpr int KSPLIT = 7;
constexpr int KHALF  = HID / KSPLIT;   // 1024 -> 64 K-tiles of 16
constexpr int LDS4   = 5;              // float4 stride (4 data + 1 pad); read
                                       // banks {0,20,8,28,16,4,24,12} distinct,
                                       // writes at b128 BW floor (8 wd/bank)

__global__ __launch_bounds__(64)
void gemm_partial(const float* __restrict__ x, const float* __restrict__ w,
                  float* __restrict__ part) {
  __shared__ float4 As4[BM * LDS4];
  __shared__ float4 Bs4[BN * LDS4];
  const int lane = threadIdx.x;
  const int e0 = blockIdx.x * BN;     // expert tile (fastest -> x reuse in L2)
  const int t0 = blockIdx.y * BM;     // token tile
  const int kp = blockIdx.z;          // k-split slice
  const size_t kbase = (size_t)kp * KHALF;

  // compute mapping: 8x8 micro-tile
  const int tx = lane & 7;            // expert sub
  const int ty = lane >> 3;           // token sub
  // staging mapping: 16 rows x 4 float4-cols per pass, 4 passes
  const int sc = lane & 3;
  const int sr = lane >> 2;

  float acc[8][8];
#pragma unroll
  for (int i = 0; i < 8; ++i)
#pragma unroll
    for (int j = 0; j < 8; ++j) acc[i][j] = 0.f;

  const float* xs = x + (size_t)(t0 + sr) * HID + kbase + 4 * sc;
  const float* wsrc = w + (size_t)(e0 + sr) * HID + kbase + 4 * sc;

  for (int k0 = 0; k0 < KHALF; k0 += BK) {
    float4 ta[4], tb[4];
#pragma unroll
    for (int p = 0; p < 4; ++p) {
      ta[p] = *(const float4*)(xs + (size_t)(16 * p) * HID + k0);
      tb[p] = *(const float4*)(wsrc + (size_t)(16 * p) * HID + k0);
    }
    __syncthreads();
#pragma unroll
    for (int p = 0; p < 4; ++p) {
      As4[(sr + 16 * p) * LDS4 + sc] = ta[p];
      Bs4[(sr + 16 * p) * LDS4 + sc] = tb[p];
    }
    __syncthreads();
#pragma unroll 1
    for (int q = 0; q < 4; ++q) {     // NOT unrolled: caps live registers
      float4 av[8];
#pragma unroll
      for (int i = 0; i < 8; ++i) av[i] = As4[(ty + 8 * i) * LDS4 + q];
#pragma unroll
      for (int j = 0; j < 8; ++j) {
        const float4 bv = Bs4[(tx + 8 * j) * LDS4 + q];
#pragma unroll
        for (int i = 0; i < 8; ++i) {
          acc[i][j] = fmaf(av[i].x, bv.x, acc[i][j]);
          acc[i][j] = fmaf(av[i].y, bv.y, acc[i][j]);
          acc[i][j] = fmaf(av[i].z, bv.z, acc[i][j]);
          acc[i][j] = fmaf(av[i].w, bv.w, acc[i][j]);
        }
      }
    }
  }

  float* pout = part + (size_t)kp * T_TOK * NEXP;
#pragma unroll
  for (int i = 0; i < 8; ++i) {
    const size_t t = t0 + ty + 8 * i;
#pragma unroll
    for (int j = 0; j < 8; ++j)
      pout[t * NEXP + (e0 + tx + 8 * j)] = acc[i][j];
  }
}

// one wave per token; lane l owns experts 4l..4l+3 entirely in registers
__global__ __launch_bounds__(256)
void routing_kernel(const float* __restrict__ part,
                    const float* __restrict__ bias,
                    float* __restrict__ out) {
  const int lane = threadIdx.x & 63;
  const int t = blockIdx.x * 4 + (threadIdx.x >> 6);
  const int e_base = 4 * lane;

  // reduce K-split partials, sigmoid, add bias
  float4 z = make_float4(0.f, 0.f, 0.f, 0.f);
#pragma unroll
  for (int kp = 0; kp < KSPLIT; ++kp) {
    float4 v = *(const float4*)(part + (size_t)kp * T_TOK * NEXP +
                                (size_t)t * NEXP + e_base);
    z.x += v.x; z.y += v.y; z.z += v.z; z.w += v.w;
  }
  float s[4], sb[4];
  const float4 b4 = *(const float4*)(bias + e_base);
  s[0] = 1.f / (1.f + expf(-z.x)); sb[0] = s[0] + b4.x;
  s[1] = 1.f / (1.f + expf(-z.y)); sb[1] = s[1] + b4.y;
  s[2] = 1.f / (1.f + expf(-z.z)); sb[2] = s[2] + b4.z;
  s[3] = 1.f / (1.f + expf(-z.w)); sb[3] = s[3] + b4.w;

  // lane-local top-2 of 4 (pairwise tournament):
  //   second-max = max( min(Ma,Mb), max(ma,mb) )  [m_loser <= min(Ma,Mb)]
  const float Ma = fmaxf(sb[0], sb[1]), ma = fminf(sb[0], sb[1]);
  const float Mb = fmaxf(sb[2], sb[3]), mb = fminf(sb[2], sb[3]);
  float m1 = fmaxf(Ma, Mb);
  float m2 = fmaxf(fminf(Ma, Mb), fmaxf(ma, mb));
  // merge (m1,m2) pairs across the 8 lanes of the group via shfl_xor 1,2,4
#pragma unroll
  for (int off = 1; off < 8; off <<= 1) {
    const float o1 = __shfl_xor(m1, off);
    const float o2 = __shfl_xor(m2, off);
    const float n1 = fmaxf(m1, o1);
    m2 = fmaxf(fminf(m1, o1), fmaxf(m2, o2));
    m1 = n1;
  }
  const float gsum = m1 + m2;   // identical across the 8 lanes of each group

  // all 8 group sums to every lane
  float gs[8];
#pragma unroll
  for (int g = 0; g < 8; ++g) gs[g] = __shfl(gsum, g * 8);

  // stable top-4 groups (strict >, ascending scan -> lowest index on ties)
  unsigned gmask = 0;
#pragma unroll
  for (int r = 0; r < 4; ++r) {
    int best = 0; float bv = -3.4e38f;
#pragma unroll
    for (int g = 0; g < 8; ++g) {
      const bool ok = (((gmask >> g) & 1u) == 0) && (gs[g] > bv);
      bv = ok ? gs[g] : bv;
      best = ok ? g : best;
    }
    gmask |= 1u << best;
  }

  // mask out unselected groups
  const bool sel = (gmask >> (lane >> 3)) & 1u;
#pragma unroll
  for (int j = 0; j < 4; ++j) sb[j] = sel ? sb[j] : -3.4e38f;

  // top-8 experts: 8 rounds of wave-argmax (ties -> lowest expert index)
  float wq[8]; float iq[8];
#pragma unroll
  for (int r = 0; r < 8; ++r) {
    float bv = sb[0]; int bi = e_base; float bs = s[0];
#pragma unroll
    for (int j = 1; j < 4; ++j) {
      const bool c = sb[j] > bv;
      bv = c ? sb[j] : bv; bi = c ? e_base + j : bi; bs = c ? s[j] : bs;
    }
#pragma unroll
    for (int off = 1; off < 64; off <<= 1) {
      const float ov = __shfl_xor(bv, off);
      const int   oi = __shfl_xor(bi, off);
      const float os = __shfl_xor(bs, off);
      const bool take = (ov > bv) || (ov == bv && oi < bi);
      bv = take ? ov : bv; bi = take ? oi : bi; bs = take ? os : bs;
    }
    wq[r] = bs; iq[r] = (float)bi;
#pragma unroll
    for (int j = 0; j < 4; ++j)
      if (e_base + j == bi) sb[j] = -3.4e38f;
  }

  float wsum = 1e-20f;
#pragma unroll
  for (int r = 0; r < 8; ++r) wsum += wq[r];
  const float scale = 2.5f / wsum;

  if (lane == 0) {
    float4* ow = (float4*)(out + (size_t)t * 8);
    ow[0] = make_float4(wq[0] * scale, wq[1] * scale, wq[2] * scale, wq[3] * scale);
    ow[1] = make_float4(wq[4] * scale, wq[5] * scale, wq[6] * scale, wq[7] * scale);
    float4* oi = (float4*)(out + (size_t)T_TOK * 8 + (size_t)t * 8);
    oi[0] = make_float4(iq[0], iq[1], iq[2], iq[3]);
    oi[1] = make_float4(iq[4], iq[5], iq[6], iq[7]);
  }
}

extern "C" void kernel_launch(void* const* d_in, const int* in_sizes, int n_in,
                              void* d_out, int out_size, void* d_ws, size_t ws_size,
                              hipStream_t stream) {
  const float* x    = (const float*)d_in[0];
  const float* w    = (const float*)d_in[1];
  const float* bias = (const float*)d_in[2];
  float* out  = (float*)d_out;
  float* part = (float*)d_ws;   // [KSPLIT][T_TOK][NEXP] fp32 = 57.3 MB

  dim3 ggrid(NEXP / BN, T_TOK / BM, KSPLIT);   // (4, 128, 7) = 3584 blocks
  hipLaunchKernelGGL(gemm_partial, ggrid, dim3(64), 0, stream, x, w, part);
  hipLaunchKernelGGL(routing_kernel, dim3(T_TOK / 4), dim3(256), 0, stream,
                     part, bias, out);
}

// Round 5
// 1097.540 us; speedup vs baseline: 4.6269x; 1.0000x over previous
//
#include <hip/hip_runtime.h>
#include <hip/hip_bf16.h>
#include <math.h>

// MoEGate: scores = sigmoid(x @ W^T); group top-2-sum -> top-4 groups -> top-8
// experts -> normalized weights * 2.5.
// Phase 1: fp32 vector GEMM (no fp32 MFMA on CDNA4), K-split=7, partials in ws.
//   R1/R3/R4 post-mortem: WRITE_SIZE ~1.7 GB at VGPR 80-132 = scratch spill.
//   The AMDGPU scheduler targets its DEFAULT max occupancy and spills to get
//   there; __launch_bounds__ min-waves does NOT stop it. The working knob is
//   amdgpu_waves_per_eu(min,max): max caps the RA occupancy target ->
//   budget 512/3 ~= 170 VGPR, live set ~110 fits, zero spill.
// Phase 2: one WAVE per token, register-resident scores, shuffle reductions.

constexpr int T_TOK = 8192;
constexpr int HID   = 7168;
constexpr int NEXP  = 256;

constexpr int BM = 64, BN = 64, BK = 16;
constexpr int KSPLIT = 7;
constexpr int KHALF  = HID / KSPLIT;   // 1024 -> 64 K-tiles of 16
constexpr int LDS4   = 5;              // float4 stride (4 data + 1 pad); av/bv
                                       // reads are 8-address broadcasts whose
                                       // base banks {0,20,8,28,16,4,24,12}
                                       // cover all 32 banks -> ~full LDS BW

__global__ __launch_bounds__(64)
__attribute__((amdgpu_waves_per_eu(2, 3)))
void gemm_partial(const float* __restrict__ x, const float* __restrict__ w,
                  float* __restrict__ part) {
  __shared__ float4 As4[BM * LDS4];
  __shared__ float4 Bs4[BN * LDS4];
  const int lane = threadIdx.x;
  const int e0 = blockIdx.x * BN;     // expert tile (fastest -> x reuse in L2)
  const int t0 = blockIdx.y * BM;     // token tile
  const int kp = blockIdx.z;          // k-split slice
  const size_t kbase = (size_t)kp * KHALF;

  // compute mapping: 8x8 micro-tile
  const int tx = lane & 7;            // expert sub
  const int ty = lane >> 3;           // token sub
  // staging mapping: 16 rows x 4 float4-cols per pass, 4 passes
  const int sc = lane & 3;
  const int sr = lane >> 2;

  float acc[8][8];
#pragma unroll
  for (int i = 0; i < 8; ++i)
#pragma unroll
    for (int j = 0; j < 8; ++j) acc[i][j] = 0.f;

  const float* xs = x + (size_t)(t0 + sr) * HID + kbase + 4 * sc;
  const float* wsrc = w + (size_t)(e0 + sr) * HID + kbase + 4 * sc;

  for (int k0 = 0; k0 < KHALF; k0 += BK) {
    float4 ta[4], tb[4];
#pragma unroll
    for (int p = 0; p < 4; ++p) {
      ta[p] = *(const float4*)(xs + (size_t)(16 * p) * HID + k0);
      tb[p] = *(const float4*)(wsrc + (size_t)(16 * p) * HID + k0);
    }
    __syncthreads();
#pragma unroll
    for (int p = 0; p < 4; ++p) {
      As4[(sr + 16 * p) * LDS4 + sc] = ta[p];
      Bs4[(sr + 16 * p) * LDS4 + sc] = tb[p];
    }
    __syncthreads();
#pragma unroll 1
    for (int q = 0; q < 4; ++q) {     // NOT unrolled: caps live registers
      float4 av[8];
#pragma unroll
      for (int i = 0; i < 8; ++i) av[i] = As4[(ty + 8 * i) * LDS4 + q];
#pragma unroll
      for (int j = 0; j < 8; ++j) {
        const float4 bv = Bs4[(tx + 8 * j) * LDS4 + q];
#pragma unroll
        for (int i = 0; i < 8; ++i) {
          acc[i][j] = fmaf(av[i].x, bv.x, acc[i][j]);
          acc[i][j] = fmaf(av[i].y, bv.y, acc[i][j]);
          acc[i][j] = fmaf(av[i].z, bv.z, acc[i][j]);
          acc[i][j] = fmaf(av[i].w, bv.w, acc[i][j]);
        }
      }
    }
  }

  float* pout = part + (size_t)kp * T_TOK * NEXP;
#pragma unroll
  for (int i = 0; i < 8; ++i) {
    const size_t t = t0 + ty + 8 * i;
#pragma unroll
    for (int j = 0; j < 8; ++j)
      pout[t * NEXP + (e0 + tx + 8 * j)] = acc[i][j];
  }
}

// one wave per token; lane l owns experts 4l..4l+3 entirely in registers
__global__ __launch_bounds__(256)
void routing_kernel(const float* __restrict__ part,
                    const float* __restrict__ bias,
                    float* __restrict__ out) {
  const int lane = threadIdx.x & 63;
  const int t = blockIdx.x * 4 + (threadIdx.x >> 6);
  const int e_base = 4 * lane;

  // reduce K-split partials, sigmoid, add bias
  float4 z = make_float4(0.f, 0.f, 0.f, 0.f);
#pragma unroll
  for (int kp = 0; kp < KSPLIT; ++kp) {
    float4 v = *(const float4*)(part + (size_t)kp * T_TOK * NEXP +
                                (size_t)t * NEXP + e_base);
    z.x += v.x; z.y += v.y; z.z += v.z; z.w += v.w;
  }
  float s[4], sb[4];
  const float4 b4 = *(const float4*)(bias + e_base);
  s[0] = 1.f / (1.f + expf(-z.x)); sb[0] = s[0] + b4.x;
  s[1] = 1.f / (1.f + expf(-z.y)); sb[1] = s[1] + b4.y;
  s[2] = 1.f / (1.f + expf(-z.z)); sb[2] = s[2] + b4.z;
  s[3] = 1.f / (1.f + expf(-z.w)); sb[3] = s[3] + b4.w;

  // lane-local top-2 of 4 (pairwise tournament):
  //   second-max = max( min(Ma,Mb), max(ma,mb) )  [m_loser <= min(Ma,Mb)]
  const float Ma = fmaxf(sb[0], sb[1]), ma = fminf(sb[0], sb[1]);
  const float Mb = fmaxf(sb[2], sb[3]), mb = fminf(sb[2], sb[3]);
  float m1 = fmaxf(Ma, Mb);
  float m2 = fmaxf(fminf(Ma, Mb), fmaxf(ma, mb));
  // merge (m1,m2) pairs across the 8 lanes of the group via shfl_xor 1,2,4
#pragma unroll
  for (int off = 1; off < 8; off <<= 1) {
    const float o1 = __shfl_xor(m1, off);
    const float o2 = __shfl_xor(m2, off);
    const float n1 = fmaxf(m1, o1);
    m2 = fmaxf(fminf(m1, o1), fmaxf(m2, o2));
    m1 = n1;
  }
  const float gsum = m1 + m2;   // identical across the 8 lanes of each group

  // all 8 group sums to every lane
  float gs[8];
#pragma unroll
  for (int g = 0; g < 8; ++g) gs[g] = __shfl(gsum, g * 8);

  // stable top-4 groups (strict >, ascending scan -> lowest index on ties)
  unsigned gmask = 0;
#pragma unroll
  for (int r = 0; r < 4; ++r) {
    int best = 0; float bv = -3.4e38f;
#pragma unroll
    for (int g = 0; g < 8; ++g) {
      const bool ok = (((gmask >> g) & 1u) == 0) && (gs[g] > bv);
      bv = ok ? gs[g] : bv;
      best = ok ? g : best;
    }
    gmask |= 1u << best;
  }

  // mask out unselected groups
  const bool sel = (gmask >> (lane >> 3)) & 1u;
#pragma unroll
  for (int j = 0; j < 4; ++j) sb[j] = sel ? sb[j] : -3.4e38f;

  // top-8 experts: 8 rounds of wave-argmax (ties -> lowest expert index)
  float wq[8]; float iq[8];
#pragma unroll
  for (int r = 0; r < 8; ++r) {
    float bv = sb[0]; int bi = e_base; float bs = s[0];
#pragma unroll
    for (int j = 1; j < 4; ++j) {
      const bool c = sb[j] > bv;
      bv = c ? sb[j] : bv; bi = c ? e_base + j : bi; bs = c ? s[j] : bs;
    }
#pragma unroll
    for (int off = 1; off < 64; off <<= 1) {
      const float ov = __shfl_xor(bv, off);
      const int   oi = __shfl_xor(bi, off);
      const float os = __shfl_xor(bs, off);
      const bool take = (ov > bv) || (ov == bv && oi < bi);
      bv = take ? ov : bv; bi = take ? oi : bi; bs = take ? os : bs;
    }
    wq[r] = bs; iq[r] = (float)bi;
#pragma unroll
    for (int j = 0; j < 4; ++j)
      if (e_base + j == bi) sb[j] = -3.4e38f;
  }

  float wsum = 1e-20f;
#pragma unroll
  for (int r = 0; r < 8; ++r) wsum += wq[r];
  const float scale = 2.5f / wsum;

  if (lane == 0) {
    float4* ow = (float4*)(out + (size_t)t * 8);
    ow[0] = make_float4(wq[0] * scale, wq[1] * scale, wq[2] * scale, wq[3] * scale);
    ow[1] = make_float4(wq[4] * scale, wq[5] * scale, wq[6] * scale, wq[7] * scale);
    float4* oi = (float4*)(out + (size_t)T_TOK * 8 + (size_t)t * 8);
    oi[0] = make_float4(iq[0], iq[1], iq[2], iq[3]);
    oi[1] = make_float4(iq[4], iq[5], iq[6], iq[7]);
  }
}

extern "C" void kernel_launch(void* const* d_in, const int* in_sizes, int n_in,
                              void* d_out, int out_size, void* d_ws, size_t ws_size,
                              hipStream_t stream) {
  const float* x    = (const float*)d_in[0];
  const float* w    = (const float*)d_in[1];
  const float* bias = (const float*)d_in[2];
  float* out  = (float*)d_out;
  float* part = (float*)d_ws;   // [KSPLIT][T_TOK][NEXP] fp32 = 57.3 MB

  dim3 ggrid(NEXP / BN, T_TOK / BM, KSPLIT);   // (4, 128, 7) = 3584 blocks
  hipLaunchKernelGGL(gemm_partial, ggrid, dim3(64), 0, stream, x, w, part);
  hipLaunchKernelGGL(routing_kernel, dim3(T_TOK / 4), dim3(256), 0, stream,
                     part, bias, out);
}

// Round 6
// 1024.542 us; speedup vs baseline: 4.9565x; 1.0712x over previous
//
#include <hip/hip_runtime.h>
#include <hip/hip_bf16.h>
#include <math.h>

// MoEGate: scores = sigmoid(x @ W^T); group top-2-sum -> top-4 groups -> top-8
// experts -> normalized weights * 2.5.
// Phase 1: fp32 vector GEMM (no fp32 MFMA on CDNA4), partials in ws.
//   R5 post-mortem: WRITE ~1.67 GB is CONSTANT across kernels = harness ws
//   poison, not spill; FETCH == x re-reads exactly. Real limiter: grid-capped
//   occupancy (14 waves/CU) + LDS latency on dependent ds_read chains.
//   Fix: 2-wave blocks on 64x64 tile (acc 32/lane, live ~60 VGPR fits the
//   RA's ~72 budget naturally) + KSPLIT=14 -> 7168 blocks -> 32 waves/CU.
// Phase 2: one WAVE per token, register-resident scores, shuffle reductions.

constexpr int T_TOK = 8192;
constexpr int HID   = 7168;
constexpr int NEXP  = 256;

constexpr int BM = 64, BN = 64, BK = 16;
constexpr int KSPLIT = 14;
constexpr int KHALF  = HID / KSPLIT;   // 512 -> 32 K-tiles of 16
constexpr int LDS4   = 5;              // float4 stride (4 data + 1 pad); bv
                                       // base banks {0,20,8,28,16,4,24,12}
                                       // cover all 32 banks; av is broadcast

__global__ __launch_bounds__(128)
void gemm_partial(const float* __restrict__ x, const float* __restrict__ w,
                  float* __restrict__ part) {
  __shared__ float4 As4[BM * LDS4];
  __shared__ float4 Bs4[BN * LDS4];
  const int tid  = threadIdx.x;
  const int wv   = tid >> 6;          // wave 0/1: token slab [32w, 32w+32)
  const int lane = tid & 63;
  const int e0 = blockIdx.x * BN;     // expert tile
  const int t0 = blockIdx.y * BM;     // token tile
  const int kp = blockIdx.z;          // k-split slice
  const size_t kbase = (size_t)kp * KHALF;

  // compute mapping: 4x8 micro-tile per lane (4 tokens x 8 experts)
  const int tx = lane & 7;            // expert sub
  const int ty = lane >> 3;           // token sub within slab (rows ty+8i)
  // staging mapping: 32 rows x 4 float4-cols per pass, 2 passes
  const int sc = tid & 3;
  const int sr = tid >> 2;            // 0..31

  float acc[4][8];
#pragma unroll
  for (int i = 0; i < 4; ++i)
#pragma unroll
    for (int j = 0; j < 8; ++j) acc[i][j] = 0.f;

  const float* xs = x + (size_t)(t0 + sr) * HID + kbase + 4 * sc;
  const float* wsrc = w + (size_t)(e0 + sr) * HID + kbase + 4 * sc;

  for (int k0 = 0; k0 < KHALF; k0 += BK) {
    float4 ta[2], tb[2];
#pragma unroll
    for (int p = 0; p < 2; ++p) {
      ta[p] = *(const float4*)(xs + (size_t)(32 * p) * HID + k0);
      tb[p] = *(const float4*)(wsrc + (size_t)(32 * p) * HID + k0);
    }
    __syncthreads();
#pragma unroll
    for (int p = 0; p < 2; ++p) {
      As4[(sr + 32 * p) * LDS4 + sc] = ta[p];
      Bs4[(sr + 32 * p) * LDS4 + sc] = tb[p];
    }
    __syncthreads();
#pragma unroll 1
    for (int q = 0; q < 4; ++q) {     // NOT unrolled: caps live registers
      float4 av[4];
#pragma unroll
      for (int i = 0; i < 4; ++i)
        av[i] = As4[(32 * wv + ty + 8 * i) * LDS4 + q];
#pragma unroll
      for (int j = 0; j < 8; ++j) {
        const float4 bv = Bs4[(tx + 8 * j) * LDS4 + q];
#pragma unroll
        for (int i = 0; i < 4; ++i) {
          acc[i][j] = fmaf(av[i].x, bv.x, acc[i][j]);
          acc[i][j] = fmaf(av[i].y, bv.y, acc[i][j]);
          acc[i][j] = fmaf(av[i].z, bv.z, acc[i][j]);
          acc[i][j] = fmaf(av[i].w, bv.w, acc[i][j]);
        }
      }
    }
  }

  float* pout = part + (size_t)kp * T_TOK * NEXP;
#pragma unroll
  for (int i = 0; i < 4; ++i) {
    const size_t t = t0 + 32 * wv + ty + 8 * i;
#pragma unroll
    for (int j = 0; j < 8; ++j)
      pout[t * NEXP + (e0 + tx + 8 * j)] = acc[i][j];
  }
}

// one wave per token; lane l owns experts 4l..4l+3 entirely in registers
__global__ __launch_bounds__(256)
void routing_kernel(const float* __restrict__ part,
                    const float* __restrict__ bias,
                    float* __restrict__ out) {
  const int lane = threadIdx.x & 63;
  const int t = blockIdx.x * 4 + (threadIdx.x >> 6);
  const int e_base = 4 * lane;

  // reduce K-split partials, sigmoid, add bias
  float4 z = make_float4(0.f, 0.f, 0.f, 0.f);
#pragma unroll
  for (int kp = 0; kp < KSPLIT; ++kp) {
    float4 v = *(const float4*)(part + (size_t)kp * T_TOK * NEXP +
                                (size_t)t * NEXP + e_base);
    z.x += v.x; z.y += v.y; z.z += v.z; z.w += v.w;
  }
  float s[4], sb[4];
  const float4 b4 = *(const float4*)(bias + e_base);
  s[0] = 1.f / (1.f + expf(-z.x)); sb[0] = s[0] + b4.x;
  s[1] = 1.f / (1.f + expf(-z.y)); sb[1] = s[1] + b4.y;
  s[2] = 1.f / (1.f + expf(-z.z)); sb[2] = s[2] + b4.z;
  s[3] = 1.f / (1.f + expf(-z.w)); sb[3] = s[3] + b4.w;

  // lane-local top-2 of 4 (pairwise tournament):
  //   second-max = max( min(Ma,Mb), max(ma,mb) )  [m_loser <= min(Ma,Mb)]
  const float Ma = fmaxf(sb[0], sb[1]), ma = fminf(sb[0], sb[1]);
  const float Mb = fmaxf(sb[2], sb[3]), mb = fminf(sb[2], sb[3]);
  float m1 = fmaxf(Ma, Mb);
  float m2 = fmaxf(fminf(Ma, Mb), fmaxf(ma, mb));
  // merge (m1,m2) pairs across the 8 lanes of the group via shfl_xor 1,2,4
#pragma unroll
  for (int off = 1; off < 8; off <<= 1) {
    const float o1 = __shfl_xor(m1, off);
    const float o2 = __shfl_xor(m2, off);
    const float n1 = fmaxf(m1, o1);
    m2 = fmaxf(fminf(m1, o1), fmaxf(m2, o2));
    m1 = n1;
  }
  const float gsum = m1 + m2;   // identical across the 8 lanes of each group

  // all 8 group sums to every lane
  float gs[8];
#pragma unroll
  for (int g = 0; g < 8; ++g) gs[g] = __shfl(gsum, g * 8);

  // stable top-4 groups (strict >, ascending scan -> lowest index on ties)
  unsigned gmask = 0;
#pragma unroll
  for (int r = 0; r < 4; ++r) {
    int best = 0; float bv = -3.4e38f;
#pragma unroll
    for (int g = 0; g < 8; ++g) {
      const bool ok = (((gmask >> g) & 1u) == 0) && (gs[g] > bv);
      bv = ok ? gs[g] : bv;
      best = ok ? g : best;
    }
    gmask |= 1u << best;
  }

  // mask out unselected groups
  const bool sel = (gmask >> (lane >> 3)) & 1u;
#pragma unroll
  for (int j = 0; j < 4; ++j) sb[j] = sel ? sb[j] : -3.4e38f;

  // top-8 experts: 8 rounds of wave-argmax (ties -> lowest expert index)
  float wq[8]; float iq[8];
#pragma unroll
  for (int r = 0; r < 8; ++r) {
    float bv = sb[0]; int bi = e_base; float bs = s[0];
#pragma unroll
    for (int j = 1; j < 4; ++j) {
      const bool c = sb[j] > bv;
      bv = c ? sb[j] : bv; bi = c ? e_base + j : bi; bs = c ? s[j] : bs;
    }
#pragma unroll
    for (int off = 1; off < 64; off <<= 1) {
      const float ov = __shfl_xor(bv, off);
      const int   oi = __shfl_xor(bi, off);
      const float os = __shfl_xor(bs, off);
      const bool take = (ov > bv) || (ov == bv && oi < bi);
      bv = take ? ov : bv; bi = take ? oi : bi; bs = take ? os : bs;
    }
    wq[r] = bs; iq[r] = (float)bi;
#pragma unroll
    for (int j = 0; j < 4; ++j)
      if (e_base + j == bi) sb[j] = -3.4e38f;
  }

  float wsum = 1e-20f;
#pragma unroll
  for (int r = 0; r < 8; ++r) wsum += wq[r];
  const float scale = 2.5f / wsum;

  if (lane == 0) {
    float4* ow = (float4*)(out + (size_t)t * 8);
    ow[0] = make_float4(wq[0] * scale, wq[1] * scale, wq[2] * scale, wq[3] * scale);
    ow[1] = make_float4(wq[4] * scale, wq[5] * scale, wq[6] * scale, wq[7] * scale);
    float4* oi = (float4*)(out + (size_t)T_TOK * 8 + (size_t)t * 8);
    oi[0] = make_float4(iq[0], iq[1], iq[2], iq[3]);
    oi[1] = make_float4(iq[4], iq[5], iq[6], iq[7]);
  }
}

extern "C" void kernel_launch(void* const* d_in, const int* in_sizes, int n_in,
                              void* d_out, int out_size, void* d_ws, size_t ws_size,
                              hipStream_t stream) {
  const float* x    = (const float*)d_in[0];
  const float* w    = (const float*)d_in[1];
  const float* bias = (const float*)d_in[2];
  float* out  = (float*)d_out;
  float* part = (float*)d_ws;   // [KSPLIT][T_TOK][NEXP] fp32 = 114.7 MB

  dim3 ggrid(NEXP / BN, T_TOK / BM, KSPLIT);   // (4, 128, 14) = 7168 blocks
  hipLaunchKernelGGL(gemm_partial, ggrid, dim3(128), 0, stream, x, w, part);
  hipLaunchKernelGGL(routing_kernel, dim3(T_TOK / 4), dim3(256), 0, stream,
                     part, bias, out);
}